// Round 1
// baseline (216.392 us; speedup 1.0000x reference)
//
#include <hip/hip_runtime.h>
#include <hip/hip_bf16.h>

typedef unsigned short u16;
typedef unsigned int u32;

// ---------------------------------------------------------------------------
// Kernel A: per-node precompute.
//   P[n][h] = sum_k z[n][k] * W1[k][h]      + b1[h]   (chunks c = 0..7)
//   Q[n][h] = sum_k z[n][k] * W1[64+k][h]             (chunks c = 8..15)
// Stored as bf16, layout PQ[n][0:64] = P, PQ[n][64:128] = Q (row = 256 B).
// blockIdx.y = chunk index c (block-uniform) so W1 indexing is wave-uniform
// -> compiler emits scalar (K$) loads for W1; z row lives in 64 VGPRs.
// ---------------------------------------------------------------------------
__global__ __launch_bounds__(256) void node_precompute(
    const float* __restrict__ z, const float* __restrict__ W1,
    const float* __restrict__ b1, u16* __restrict__ pq, int nNodes)
{
    const int n = blockIdx.x * 256 + threadIdx.x;
    const int c = blockIdx.y;              // 0..15, uniform per block
    if (n >= nNodes) return;

    // W1 is [128][64] row-major (x @ W1). Chunk c -> output cols (c&7)*8..+8,
    // input-row offset (c>>3)*64 (top half for P, bottom half for Q).
    const float* wbase = W1 + (size_t)((c >> 3) * 64) * 64 + (c & 7) * 8;

    // Load z[n][0:64] into registers (16 x float4).
    float zr[64];
    const float4* z4 = (const float4*)(z + (size_t)n * 64);
#pragma unroll
    for (int i = 0; i < 16; ++i) {
        float4 v = z4[i];
        zr[4 * i + 0] = v.x; zr[4 * i + 1] = v.y;
        zr[4 * i + 2] = v.z; zr[4 * i + 3] = v.w;
    }

    float acc[8];
#pragma unroll
    for (int h = 0; h < 8; ++h)
        acc[h] = (c < 8) ? b1[(c & 7) * 8 + h] : 0.0f;

#pragma unroll
    for (int k = 0; k < 64; ++k) {
        const float zk = zr[k];
#pragma unroll
        for (int h = 0; h < 8; ++h)
            acc[h] = fmaf(zk, wbase[(size_t)k * 64 + h], acc[h]);
    }

    // Pack 8 results to bf16 (RNE) and store as one 16 B write.
    u16 ob[8];
#pragma unroll
    for (int h = 0; h < 8; ++h) {
        __hip_bfloat16 b = __float2bfloat16(acc[h]);
        ob[h] = *(u16*)&b;
    }
    *((uint4*)(pq + (size_t)n * 128 + c * 8)) = *(const uint4*)ob;
}

// ---------------------------------------------------------------------------
// Kernel B: per-edge MLP tail.
//   out[e] = b2 + sum_h W2[h] * relu(P[i][h] + Q[j][h])
// One thread per edge; 8+8 uint4 loads gather the two 128 B bf16 rows.
// ---------------------------------------------------------------------------
__global__ __launch_bounds__(256) void edge_mlp(
    const int* __restrict__ e0, const int* __restrict__ e1,
    const u16* __restrict__ pq, const float* __restrict__ W2,
    const float* __restrict__ b2, float* __restrict__ out, int E)
{
    const int e = blockIdx.x * 256 + threadIdx.x;
    if (e >= E) return;

    const int i = e0[e];
    const int j = e1[e];
    const uint4* Pi = (const uint4*)(pq + (size_t)i * 128);       // P row
    const uint4* Qj = (const uint4*)(pq + (size_t)j * 128 + 64);  // Q row

    uint4 p[8], q[8];
#pragma unroll
    for (int t = 0; t < 8; ++t) p[t] = Pi[t];
#pragma unroll
    for (int t = 0; t < 8; ++t) q[t] = Qj[t];

    const u16* pp = (const u16*)p;
    const u16* qq = (const u16*)q;

    float acc = 0.0f;
#pragma unroll
    for (int h = 0; h < 64; ++h) {
        float a = __uint_as_float((u32)pp[h] << 16)
                + __uint_as_float((u32)qq[h] << 16);
        a = fmaxf(a, 0.0f);
        acc = fmaf(a, W2[h], acc);
    }
    out[e] = acc + b2[0];
}

// ---------------------------------------------------------------------------
extern "C" void kernel_launch(void* const* d_in, const int* in_sizes, int n_in,
                              void* d_out, int out_size, void* d_ws, size_t ws_size,
                              hipStream_t stream) {
    const float* z  = (const float*)d_in[0];
    const int*   eg = (const int*)d_in[1];
    const float* W1 = (const float*)d_in[2];
    const float* b1 = (const float*)d_in[3];
    const float* W2 = (const float*)d_in[4];
    const float* b2 = (const float*)d_in[5];
    float* out = (float*)d_out;

    const int nNodes = in_sizes[0] / 64;   // 100000
    const int E      = in_sizes[1] / 2;    // 1000000

    u16* pq = (u16*)d_ws;                  // needs nNodes*128*2 = 25.6 MB

    dim3 gA((nNodes + 255) / 256, 16);
    node_precompute<<<gA, dim3(256), 0, stream>>>(z, W1, b1, pq, nNodes);

    dim3 gB((E + 255) / 256);
    edge_mlp<<<gB, dim3(256), 0, stream>>>(eg, eg + E, pq, W2, b2, out, E);
}